// Round 3
// baseline (9831.751 us; speedup 1.0000x reference)
//
#include <hip/hip_runtime.h>
#include <stdint.h>

typedef __attribute__((ext_vector_type(4))) float f32x4;
typedef __attribute__((ext_vector_type(8))) short s16x8;
typedef __attribute__((ext_vector_type(4))) unsigned short u16x4;
typedef unsigned long long u64c;

#define T_SEQ 1024
#define HID 512

__device__ __forceinline__ unsigned short f2bf(float f) {
  uint32_t u = __float_as_uint(f);
  u += 0x7fffu + ((u >> 16) & 1u);  // round-to-nearest-even
  return (unsigned short)(u >> 16);
}
__device__ __forceinline__ float sigf(float x) { return 1.f / (1.f + __expf(-x)); }
__device__ __forceinline__ float tanhfast(float x) {
  float e = __expf(2.f * x);
  return (e - 1.f) / (e + 1.f);
}

#define ALOAD(p) __hip_atomic_load((p), __ATOMIC_RELAXED, __HIP_MEMORY_SCOPE_AGENT)
#define ASTORE(p, v) __hip_atomic_store((p), (v), __ATOMIC_RELAXED, __HIP_MEMORY_SCOPE_AGENT)

union frag_u { u64c q[2]; s16x8 v; };
__device__ __forceinline__ s16x8 zero_frag() {
  frag_u f; f.q[0] = 0; f.q[1] = 0; return f.v;
}

#define GLL(gp, lp)                                                      \
  __builtin_amdgcn_global_load_lds(                                     \
      (const __attribute__((address_space(1))) void*)(gp),              \
      (__attribute__((address_space(3))) void*)(lp), 16, 0, 0)

// ---------------- small prep kernels ----------------
__global__ __launch_bounds__(256) void embed_kernel(const int* __restrict__ inp,
                                                    const float* __restrict__ wte,
                                                    unsigned short* __restrict__ xbf) {
  const int m = blockIdx.x;  // m = b*1024 + t
  const int idx = inp[m];
  const float* src = wte + (size_t)idx * HID;
  unsigned short* dst = xbf + (size_t)m * HID;
  const int e = threadIdx.x;
  dst[e] = f2bf(src[e]);
  dst[e + 256] = f2bf(src[e + 256]);
}

__global__ __launch_bounds__(256) void cvt_bf16_kernel(const float* __restrict__ src,
                                                       unsigned short* __restrict__ dst,
                                                       int n4) {
  const int i = blockIdx.x * 256 + threadIdx.x;
  if (i >= n4) return;
  f32x4 v = ((const f32x4*)src)[i];
  u16x4 o;
  o.x = f2bf(v.x); o.y = f2bf(v.y); o.z = f2bf(v.z); o.w = f2bf(v.w);
  ((u16x4*)dst)[i] = o;
}

__global__ __launch_bounds__(256) void bias_sum_kernel(const float* __restrict__ a,
                                                       const float* __restrict__ b,
                                                       float* __restrict__ o, int n) {
  const int i = blockIdx.x * 256 + threadIdx.x;
  if (i < n) o[i] = a[i] + b[i];
}

// ---------------- bf16 MFMA GEMM:  C[m][n] = sum_k A[m][k]*B[n][k] + bias[n] ----------------
// MODE 0: C row = m. MODE 1: m = t*8+b -> C row = b*1024+t. MODE 2: m = b*1024+t -> C row = t*8+b.
template <int MODE>
__global__ __launch_bounds__(256) void gemm_bt(const unsigned short* __restrict__ A,
                                               const unsigned short* __restrict__ B,
                                               float* __restrict__ C,
                                               const float* __restrict__ bias,
                                               int M, int N, int K) {
  __shared__ unsigned short As[128 * 32];
  __shared__ unsigned short Bs[128 * 32];
  const int nTiles = N >> 7;
  const int mt = blockIdx.x / nTiles;
  const int nt = blockIdx.x - mt * nTiles;
  const int m0 = mt << 7, n0 = nt << 7;
  const int tid = threadIdx.x;
  const int wave = tid >> 6, lane = tid & 63;
  const int wm = wave >> 1, wn = wave & 1;

  const int c1 = wave * 64 + lane;
  const int c2 = 256 + c1;
  const unsigned short* gA1 = A + (size_t)(m0 + (c1 >> 2)) * K + (c1 & 3) * 8;
  const unsigned short* gA2 = A + (size_t)(m0 + (c2 >> 2)) * K + (c2 & 3) * 8;
  const unsigned short* gB1 = B + (size_t)(n0 + (c1 >> 2)) * K + (c1 & 3) * 8;
  const unsigned short* gB2 = B + (size_t)(n0 + (c2 >> 2)) * K + (c2 & 3) * 8;
  unsigned short* lA1 = As + wave * 512;
  unsigned short* lA2 = As + 2048 + wave * 512;
  unsigned short* lB1 = Bs + wave * 512;
  unsigned short* lB2 = Bs + 2048 + wave * 512;

  f32x4 acc[4][4] = {};
  const int row_lo = lane & 15;
  const int kq = (lane >> 4) * 8;

  for (int k0 = 0; k0 < K; k0 += 32) {
    GLL(gA1 + k0, lA1);
    GLL(gA2 + k0, lA2);
    GLL(gB1 + k0, lB1);
    GLL(gB2 + k0, lB2);
    __syncthreads();
    s16x8 af[4], bfr[4];
#pragma unroll
    for (int f = 0; f < 4; ++f) {
      af[f] = *(const s16x8*)(As + (wm * 64 + f * 16 + row_lo) * 32 + kq);
      bfr[f] = *(const s16x8*)(Bs + (wn * 64 + f * 16 + row_lo) * 32 + kq);
    }
#pragma unroll
    for (int i = 0; i < 4; ++i)
#pragma unroll
      for (int j = 0; j < 4; ++j)
        acc[i][j] = __builtin_amdgcn_mfma_f32_16x16x32_bf16(af[i], bfr[j], acc[i][j], 0, 0, 0);
    __syncthreads();
  }

  float bv[4];
#pragma unroll
  for (int j = 0; j < 4; ++j) bv[j] = bias[n0 + wn * 64 + j * 16 + row_lo];
  const int rbase = (lane >> 4) * 4;
#pragma unroll
  for (int i = 0; i < 4; ++i) {
#pragma unroll
    for (int r = 0; r < 4; ++r) {
      const int m = m0 + wm * 64 + i * 16 + rbase + r;
      const size_t row = MODE == 1 ? ((size_t)(m & 7) * T_SEQ + (m >> 3))
                       : MODE == 2 ? ((size_t)(m & (T_SEQ - 1)) * 8 + (m >> 10))
                                   : (size_t)m;
      float* cp = C + row * (size_t)N;
#pragma unroll
      for (int j = 0; j < 4; ++j) cp[n0 + wn * 64 + j * 16 + row_lo] = acc[i][j][r] + bv[j];
    }
  }
}

// ---------------- persistent 2-layer LSTM ----------------
// 64 WGs x 256 thr (1 WG/CU). WGs 0..31: layer 1 (16 units each); 32..63: layer 2 (16 units).
// Per-WG flag cachelines (no contended atomics). Weights VGPR-resident as B-fragments.
// h exchanged via packed-bf16 relaxed agent atomics; A-fragments loaded global->reg (8B atomics).
template <bool IS_L1>
__device__ __forceinline__ void lstm_side(
    int wg, int tid,
    const float* __restrict__ xg1t,          // [t*8+b][2048] (L1 only)
    const unsigned short* __restrict__ Wa,   // L1: whh1 ; L2: wih2
    const unsigned short* __restrict__ Wb,   // L2: whh2
    const float* __restrict__ bias2,         // b_ih+b_hh layer 2 (L2 only)
    unsigned int* __restrict__ h1bf, unsigned int* __restrict__ h2bf,
    unsigned int* __restrict__ flags1, unsigned int* __restrict__ flags2,
    float* GT) {
  constexpr int NKT = IS_L1 ? 16 : 32;
  const int wave = tid >> 6, lane = tid & 63;
  const int col = lane & 15, grp = lane >> 4;
  const int u0 = wg * 16;
  const int koff = grp * 8;
  const int ab = lane & 7;

  // ---- resident weight B-fragments: wave = gate, col = unit ----
  s16x8 bfr[NKT];
  {
    const int grow = wave * 512 + u0 + col;
#pragma unroll
    for (int kt = 0; kt < NKT; ++kt) {
      const unsigned short* W = (IS_L1 || kt < 16) ? Wa : Wb;
      const int kk = (kt & 15) * 32 + koff;
      bfr[kt] = *(const s16x8*)(W + (size_t)grow * 512 + kk);
    }
  }

  // ---- pointwise constants (wave 0): 2 states/lane, u = r*8 + (lane>>3), b = lane&7 ----
  const int pb = lane & 7, ps = lane >> 3;
  float bias_g[2][4];
  if constexpr (!IS_L1) {
    if (wave == 0) {
#pragma unroll
      for (int r = 0; r < 2; ++r)
#pragma unroll
        for (int g = 0; g < 4; ++g)
          bias_g[r][g] = bias2[g * 512 + u0 + r * 8 + ps];
    }
  }
  float c0 = 0.f, c1 = 0.f;

  unsigned int* myflag = (IS_L1 ? flags1 : flags2) + wg * 16;
  const unsigned int* pollp =
      IS_L1 ? (flags1 + (lane & 31) * 16)
            : (lane < 32 ? flags1 + lane * 16 : flags2 + (lane - 32) * 16);

  for (int t = 0; t < T_SEQ; ++t) {
    // ---- xg prefetch (L1 wave 0) before polling ----
    float xv[2][4];
    if constexpr (IS_L1) {
      if (wave == 0) {
#pragma unroll
        for (int r = 0; r < 2; ++r)
#pragma unroll
          for (int g = 0; g < 4; ++g)
            xv[r][g] = xg1t[(size_t)(t * 8 + pb) * 2048 + g * 512 + u0 + r * 8 + ps];
      }
    }
    // ---- poll producer flags (parallel: one flag per lane, ballot) ----
    if (!IS_L1 || t > 0) {
      const unsigned int tgt =
          IS_L1 ? (unsigned)t : (lane < 32 ? (unsigned)(t + 1) : (unsigned)t);
      while (true) {
        unsigned int v = ALOAD(pollp);
        if (__ballot(v >= tgt) == ~0ULL) break;
        __builtin_amdgcn_s_sleep(1);
      }
    }
    // ---- A-fragments direct from global (8B relaxed agent atomics) ----
    s16x8 afr[NKT];
    if constexpr (IS_L1) {
      if (t > 0) {
        const u64c* hp =
            (const u64c*)((const unsigned short*)h1bf + ((size_t)(t - 1) * 8 + ab) * 512 + koff);
#pragma unroll
        for (int kt = 0; kt < 16; ++kt) {
          frag_u f; f.q[0] = ALOAD(hp + kt * 8); f.q[1] = ALOAD(hp + kt * 8 + 1);
          afr[kt] = f.v;
        }
      } else {
#pragma unroll
        for (int kt = 0; kt < 16; ++kt) afr[kt] = zero_frag();
      }
    } else {
      const u64c* hp1 =
          (const u64c*)((const unsigned short*)h1bf + ((size_t)t * 8 + ab) * 512 + koff);
#pragma unroll
      for (int kt = 0; kt < 16; ++kt) {
        frag_u f; f.q[0] = ALOAD(hp1 + kt * 8); f.q[1] = ALOAD(hp1 + kt * 8 + 1);
        afr[kt] = f.v;
      }
      if (t > 0) {
        const u64c* hp2 =
            (const u64c*)((const unsigned short*)h2bf + ((size_t)(t - 1) * 8 + ab) * 512 + koff);
#pragma unroll
        for (int kt = 0; kt < 16; ++kt) {
          frag_u f; f.q[0] = ALOAD(hp2 + kt * 8); f.q[1] = ALOAD(hp2 + kt * 8 + 1);
          afr[16 + kt] = f.v;
        }
      } else {
#pragma unroll
        for (int kt = 16; kt < 32; ++kt) afr[kt] = zero_frag();
      }
    }
    // ---- MFMA: full-K per wave, 4 independent accumulator chains ----
    f32x4 a0 = {}, a1 = {}, a2 = {}, a3 = {};
#pragma unroll
    for (int kt = 0; kt < NKT; kt += 4) {
      a0 = __builtin_amdgcn_mfma_f32_16x16x32_bf16(afr[kt], bfr[kt], a0, 0, 0, 0);
      a1 = __builtin_amdgcn_mfma_f32_16x16x32_bf16(afr[kt + 1], bfr[kt + 1], a1, 0, 0, 0);
      a2 = __builtin_amdgcn_mfma_f32_16x16x32_bf16(afr[kt + 2], bfr[kt + 2], a2, 0, 0, 0);
      a3 = __builtin_amdgcn_mfma_f32_16x16x32_bf16(afr[kt + 3], bfr[kt + 3], a3, 0, 0, 0);
    }
    f32x4 acc = (a0 + a1) + (a2 + a3);
    // ---- gate exchange: GT[gate][unit][batch]; C/D: col(lane&15)=unit, row=batch ----
    if (grp < 2) *(f32x4*)(GT + wave * 128 + col * 8 + grp * 4) = acc;
    __syncthreads();
    // (no 2nd barrier: next-step GT overwrite is gated by this WG's own flag)
    if (wave == 0) {
      float hv[2];
#pragma unroll
      for (int r = 0; r < 2; ++r) {
        const int u = r * 8 + ps;
        float gi = GT[0 * 128 + u * 8 + pb];
        float gf = GT[1 * 128 + u * 8 + pb];
        float gg = GT[2 * 128 + u * 8 + pb];
        float go = GT[3 * 128 + u * 8 + pb];
        if constexpr (IS_L1) {
          gi += xv[r][0]; gf += xv[r][1]; gg += xv[r][2]; go += xv[r][3];
        } else {
          gi += bias_g[r][0]; gf += bias_g[r][1]; gg += bias_g[r][2]; go += bias_g[r][3];
        }
        float& cc = r ? c1 : c0;
        cc = sigf(gf) * cc + sigf(gi) * tanhfast(gg);
        hv[r] = sigf(go) * tanhfast(cc);
      }
      unsigned int* hout = IS_L1 ? h1bf : h2bf;
#pragma unroll
      for (int r = 0; r < 2; ++r) {
        unsigned int hb16 = f2bf(hv[r]);
        unsigned int partner = (unsigned int)__shfl_xor((int)hb16, 8);
        if ((ps & 1) == 0) {
          unsigned int pack = (hb16 & 0xffffu) | (partner << 16);
          ASTORE(hout + (size_t)(t * 8 + pb) * 256 + wg * 8 + r * 4 + (ps >> 1), pack);
        }
      }
      asm volatile("s_waitcnt vmcnt(0)" ::: "memory");  // h stores ack'd at coherence point
      if (lane == 0) ASTORE(myflag, (unsigned int)(t + 1));
    }
  }
}

__global__ __launch_bounds__(256, 1) void lstm_kernel(
    const float* __restrict__ xg1t,
    const unsigned short* __restrict__ whh1,
    const unsigned short* __restrict__ wih2,
    const unsigned short* __restrict__ whh2,
    const float* __restrict__ bias2,
    unsigned int* __restrict__ h1bf, unsigned int* __restrict__ h2bf,
    unsigned int* __restrict__ flags) {
  __shared__ float GT[512];
  const int wg = blockIdx.x, tid = threadIdx.x;
  if (wg < 32)
    lstm_side<true>(wg, tid, xg1t, whh1, nullptr, nullptr,
                    h1bf, h2bf, flags, flags + 512, GT);
  else
    lstm_side<false>(wg - 32, tid, xg1t, wih2, whh2, bias2,
                     h1bf, h2bf, flags, flags + 512, GT);
}

// ---------------- host launch ----------------
extern "C" void kernel_launch(void* const* d_in, const int* in_sizes, int n_in,
                              void* d_out, int out_size, void* d_ws, size_t ws_size,
                              hipStream_t stream) {
  (void)in_sizes; (void)n_in; (void)out_size; (void)ws_size;
  const int* inp = (const int*)d_in[0];
  const float* wte = (const float*)d_in[1];
  const float* W_ih = (const float*)d_in[2];
  const float* W_hh = (const float*)d_in[3];
  const float* b_ih = (const float*)d_in[4];
  const float* b_hh = (const float*)d_in[5];
  const float* fc_w = (const float*)d_in[6];
  const float* fc_b = (const float*)d_in[7];
  float* out = (float*)d_out;

  // Large intermediates inside d_out (1 GB; fully overwritten by final FC GEMM afterwards).
  char* ob = (char*)d_out;
  float* xg1t = (float*)(ob);                                    // 64 MiB  [t*8+b][2048]
  unsigned int* h1bf = (unsigned int*)(ob + (64u << 20));        //  8 MiB  [t*8+b][256] packed bf16
  unsigned short* whh_bf = (unsigned short*)(ob + (72u << 20));  //  4 MiB
  unsigned short* wih_bf = (unsigned short*)(ob + (76u << 20));  //  4 MiB
  unsigned short* x_bf = (unsigned short*)(ob + (80u << 20));    //  8 MiB

  char* ws = (char*)d_ws;  // within proven 43 MiB footprint
  unsigned short* fcw_bf = (unsigned short*)(ws);                //  31.25 MiB
  float* bias12 = (float*)(ws + (32u << 20));                    //  16 KiB (both layers)
  unsigned int* flags = (unsigned int*)(ws + (33u << 20));       //  4 KiB (2 x 32 x 64B)
  unsigned int* h2bf = (unsigned int*)(ws + (35u << 20));        //  8 MiB [t*8+b][256]

  hipMemsetAsync(flags, 0, 4096, stream);
  embed_kernel<<<8192, 256, 0, stream>>>(inp, wte, x_bf);
  cvt_bf16_kernel<<<2048, 256, 0, stream>>>(W_ih, wih_bf, 2 * 2048 * 512 / 4);
  cvt_bf16_kernel<<<2048, 256, 0, stream>>>(W_hh, whh_bf, 2 * 2048 * 512 / 4);
  cvt_bf16_kernel<<<16000, 256, 0, stream>>>(fc_w, fcw_bf, 32000 * 512 / 4);
  bias_sum_kernel<<<16, 256, 0, stream>>>(b_ih, b_hh, bias12, 4096);
  // xg1t[t*8+b][g] = x @ W_ih0^T + (b_ih0 + b_hh0)
  gemm_bt<2><<<64 * 16, 256, 0, stream>>>(x_bf, wih_bf, xg1t, bias12, 8192, 2048, 512);
  lstm_kernel<<<64, 256, 0, stream>>>(xg1t, whh_bf, wih_bf + (size_t)2048 * 512,
                                      whh_bf + (size_t)2048 * 512, bias12 + 2048,
                                      h1bf, h2bf, flags);
  // logits = h2 @ fc_w^T + fc_b  (A rows t*8+b -> C rows b*1024+t)
  gemm_bt<1><<<64 * 250, 256, 0, stream>>>((const unsigned short*)h2bf, fcw_bf, out, fc_b,
                                           8192, 32000, 512);
}

// Round 4
// 4934.739 us; speedup vs baseline: 1.9924x; 1.9924x over previous
//
#include <hip/hip_runtime.h>
#include <stdint.h>

typedef __attribute__((ext_vector_type(4))) float f32x4;
typedef __attribute__((ext_vector_type(8))) short s16x8;
typedef __attribute__((ext_vector_type(4))) unsigned short u16x4;
typedef __attribute__((ext_vector_type(4))) unsigned int u32x4;

#define T_SEQ 1024
#define HID 512

__device__ __forceinline__ unsigned short f2bf(float f) {
  uint32_t u = __float_as_uint(f);
  u += 0x7fffu + ((u >> 16) & 1u);  // round-to-nearest-even
  return (unsigned short)(u >> 16);
}
__device__ __forceinline__ float sigf(float x) { return 1.f / (1.f + __expf(-x)); }
__device__ __forceinline__ float tanhfast(float x) {
  float e = __expf(2.f * x);
  return (e - 1.f) / (e + 1.f);
}

#define ASTORE(p, v) __hip_atomic_store((p), (v), __ATOMIC_RELAXED, __HIP_MEMORY_SCOPE_AGENT)

// Coherent 16B load: bypass L1 (sc0) and the non-coherent per-XCD L2 (sc1) -> served by MALL.
__device__ __forceinline__ u32x4 load_coh16(const unsigned int* p) {
  u32x4 r;
  asm volatile("global_load_dwordx4 %0, %1, off sc0 sc1" : "=v"(r) : "v"(p) : "memory");
  return r;
}
#define VM_WAIT0 do { asm volatile("s_waitcnt vmcnt(0)" ::: "memory"); \
                      __builtin_amdgcn_sched_barrier(0); } while (0)

#define GLL(gp, lp)                                                      \
  __builtin_amdgcn_global_load_lds(                                     \
      (const __attribute__((address_space(1))) void*)(gp),              \
      (__attribute__((address_space(3))) void*)(lp), 16, 0, 0)

// ---------------- small prep kernels ----------------
__global__ __launch_bounds__(256) void embed_kernel(const int* __restrict__ inp,
                                                    const float* __restrict__ wte,
                                                    unsigned short* __restrict__ xbf) {
  const int m = blockIdx.x;  // m = b*1024 + t
  const int idx = inp[m];
  const float* src = wte + (size_t)idx * HID;
  unsigned short* dst = xbf + (size_t)m * HID;
  const int e = threadIdx.x;
  dst[e] = f2bf(src[e]);
  dst[e + 256] = f2bf(src[e + 256]);
}

__global__ __launch_bounds__(256) void cvt_bf16_kernel(const float* __restrict__ src,
                                                       unsigned short* __restrict__ dst,
                                                       int n4) {
  const int i = blockIdx.x * 256 + threadIdx.x;
  if (i >= n4) return;
  f32x4 v = ((const f32x4*)src)[i];
  u16x4 o;
  o.x = f2bf(v.x); o.y = f2bf(v.y); o.z = f2bf(v.z); o.w = f2bf(v.w);
  ((u16x4*)dst)[i] = o;
}

__global__ __launch_bounds__(256) void bias_sum_kernel(const float* __restrict__ a,
                                                       const float* __restrict__ b,
                                                       float* __restrict__ o, int n) {
  const int i = blockIdx.x * 256 + threadIdx.x;
  if (i < n) o[i] = a[i] + b[i];
}

// ---------------- bf16 MFMA GEMM:  C[m][n] = sum_k A[m][k]*B[n][k] + bias[n] ----------------
// MODE 0: C row = m. MODE 1: m = t*8+b -> C row = b*1024+t. MODE 2: m = b*1024+t -> C row = t*8+b.
template <int MODE>
__global__ __launch_bounds__(256) void gemm_bt(const unsigned short* __restrict__ A,
                                               const unsigned short* __restrict__ B,
                                               float* __restrict__ C,
                                               const float* __restrict__ bias,
                                               int M, int N, int K) {
  __shared__ unsigned short As[128 * 32];
  __shared__ unsigned short Bs[128 * 32];
  const int nTiles = N >> 7;
  const int mt = blockIdx.x / nTiles;
  const int nt = blockIdx.x - mt * nTiles;
  const int m0 = mt << 7, n0 = nt << 7;
  const int tid = threadIdx.x;
  const int wave = tid >> 6, lane = tid & 63;
  const int wm = wave >> 1, wn = wave & 1;

  const int c1 = wave * 64 + lane;
  const int c2 = 256 + c1;
  const unsigned short* gA1 = A + (size_t)(m0 + (c1 >> 2)) * K + (c1 & 3) * 8;
  const unsigned short* gA2 = A + (size_t)(m0 + (c2 >> 2)) * K + (c2 & 3) * 8;
  const unsigned short* gB1 = B + (size_t)(n0 + (c1 >> 2)) * K + (c1 & 3) * 8;
  const unsigned short* gB2 = B + (size_t)(n0 + (c2 >> 2)) * K + (c2 & 3) * 8;
  unsigned short* lA1 = As + wave * 512;
  unsigned short* lA2 = As + 2048 + wave * 512;
  unsigned short* lB1 = Bs + wave * 512;
  unsigned short* lB2 = Bs + 2048 + wave * 512;

  f32x4 acc[4][4] = {};
  const int row_lo = lane & 15;
  const int kq = (lane >> 4) * 8;

  for (int k0 = 0; k0 < K; k0 += 32) {
    GLL(gA1 + k0, lA1);
    GLL(gA2 + k0, lA2);
    GLL(gB1 + k0, lB1);
    GLL(gB2 + k0, lB2);
    __syncthreads();
    s16x8 af[4], bfr[4];
#pragma unroll
    for (int f = 0; f < 4; ++f) {
      af[f] = *(const s16x8*)(As + (wm * 64 + f * 16 + row_lo) * 32 + kq);
      bfr[f] = *(const s16x8*)(Bs + (wn * 64 + f * 16 + row_lo) * 32 + kq);
    }
#pragma unroll
    for (int i = 0; i < 4; ++i)
#pragma unroll
      for (int j = 0; j < 4; ++j)
        acc[i][j] = __builtin_amdgcn_mfma_f32_16x16x32_bf16(af[i], bfr[j], acc[i][j], 0, 0, 0);
    __syncthreads();
  }

  float bv[4];
#pragma unroll
  for (int j = 0; j < 4; ++j) bv[j] = bias[n0 + wn * 64 + j * 16 + row_lo];
  const int rbase = (lane >> 4) * 4;
#pragma unroll
  for (int i = 0; i < 4; ++i) {
#pragma unroll
    for (int r = 0; r < 4; ++r) {
      const int m = m0 + wm * 64 + i * 16 + rbase + r;
      const size_t row = MODE == 1 ? ((size_t)(m & 7) * T_SEQ + (m >> 3))
                       : MODE == 2 ? ((size_t)(m & (T_SEQ - 1)) * 8 + (m >> 10))
                                   : (size_t)m;
      float* cp = C + row * (size_t)N;
#pragma unroll
      for (int j = 0; j < 4; ++j) cp[n0 + wn * 64 + j * 16 + row_lo] = acc[i][j][r] + bv[j];
    }
  }
}

// ---------------- persistent 2-layer LSTM ----------------
// 64 WGs x 256 thr (32/layer, 16 hidden units each). Sync = tagged data: h value u32 =
// bf16 | (t+1)<<16, stored relaxed-agent (MALL), polled with sc0|sc1 loads. One MALL round
// trip per step. Staging: 256 thr cooperatively poll+load the 8x512 tagged tile, untag,
// pack, ds_write_b128 into XOR-swizzled LDS; MFMA A-frags via conflict-free ds_read_b128.
template <bool IS_L1>
__device__ __forceinline__ void lstm_side(
    int wg, int tid,
    const float* __restrict__ xg1t,          // [t*8+b][2048] (L1 only)
    const unsigned short* __restrict__ Wa,   // L1: whh1 ; L2: wih2
    const unsigned short* __restrict__ Wb,   // L2: whh2
    const float* __restrict__ bias2,         // b_ih+b_hh layer 2 (L2 only)
    unsigned int* __restrict__ h1T,          // [t][8][512] tagged u32
    unsigned int* __restrict__ h2T,
    unsigned short* __restrict__ h2out,      // [t*8+b][512] bf16 (FC input)
    char* hlds, float* GT) {
  constexpr int NKT = IS_L1 ? 16 : 32;
  constexpr int RB = IS_L1 ? 1024 : 2048;  // LDS row bytes
  const int g = tid >> 6, l = tid & 63;    // wave = gate
  const int unit = l & 15, grp = l >> 4;
  const int u0 = wg * 16;
  const int row = l & 7;                    // A-frag row (lanes 8-15 dup rows 0-7)

  // ---- resident weight B-fragments ----
  s16x8 bfr[NKT];
  {
    const size_t grow = (size_t)(g * 512 + u0 + unit) * 512;
#pragma unroll
    for (int kt = 0; kt < NKT; ++kt) {
      const unsigned short* W = (IS_L1 || kt < 16) ? Wa : Wb;
      bfr[kt] = *(const s16x8*)(W + grow + (kt & 15) * 32 + grp * 8);
    }
  }

  // ---- staging ids: thread -> (row sr, 16-u32 chunk sc) ----
  const int sr = tid & 7, sc = tid >> 3;
  const int sb0 = (sr * RB + sc * 32) ^ (sr << 4);
  const int sb1 = (sr * RB + sc * 32 + 16) ^ (sr << 4);
  const int sb2 = (sr * RB + 1024 + sc * 32) ^ (sr << 4);       // L2: h2 half
  const int sb3 = (sr * RB + 1024 + sc * 32 + 16) ^ (sr << 4);

  // ---- pointwise constants (wave 0): lane -> (u = r*8 + pu, b = pb), r = 0,1 ----
  const int pb = l & 7, pu = l >> 3;
  float bias_g[2][4];
  if constexpr (!IS_L1) {
    if (g == 0) {
#pragma unroll
      for (int r = 0; r < 2; ++r)
#pragma unroll
        for (int gg = 0; gg < 4; ++gg)
          bias_g[r][gg] = bias2[gg * 512 + u0 + r * 8 + pu];
    }
  }
  float cst0 = 0.f, cst1 = 0.f;

  for (int t = 0; t < T_SEQ; ++t) {
    // ---- xg prefetch (L1 wave 0) ----
    float xv[2][4];
    if constexpr (IS_L1) {
      if (g == 0) {
#pragma unroll
        for (int r = 0; r < 2; ++r)
#pragma unroll
          for (int gg = 0; gg < 4; ++gg)
            xv[r][gg] = xg1t[(size_t)(t * 8 + pb) * 2048 + gg * 512 + u0 + r * 8 + pu];
      }
    }

    // ---- poll + stage into swizzled LDS ----
    if constexpr (IS_L1) {
      u32x4 w0 = {}, w1 = {};
      if (t > 0) {
        const unsigned int* src = h1T + (size_t)(t - 1) * 4096 + sr * 512 + sc * 16;
        const unsigned int tg = (unsigned int)t;
        u32x4 d0, d1, d2, d3;
        for (;;) {
          d0 = load_coh16(src); d1 = load_coh16(src + 4);
          d2 = load_coh16(src + 8); d3 = load_coh16(src + 12);
          VM_WAIT0;
          bool ok = true;
#pragma unroll
          for (int j = 0; j < 4; ++j) {
            ok &= (d0[j] >> 16) == tg; ok &= (d1[j] >> 16) == tg;
            ok &= (d2[j] >> 16) == tg; ok &= (d3[j] >> 16) == tg;
          }
          if (__ballot(ok) == ~0ULL) break;
          __builtin_amdgcn_s_sleep(1);
        }
        w0 = u32x4{(d0[0] & 0xffffu) | (d0[1] << 16), (d0[2] & 0xffffu) | (d0[3] << 16),
                   (d1[0] & 0xffffu) | (d1[1] << 16), (d1[2] & 0xffffu) | (d1[3] << 16)};
        w1 = u32x4{(d2[0] & 0xffffu) | (d2[1] << 16), (d2[2] & 0xffffu) | (d2[3] << 16),
                   (d3[0] & 0xffffu) | (d3[1] << 16), (d3[2] & 0xffffu) | (d3[3] << 16)};
      }
      *(u32x4*)(hlds + sb0) = w0;
      *(u32x4*)(hlds + sb1) = w1;
    } else {
      const unsigned int* src1 = h1T + (size_t)t * 4096 + sr * 512 + sc * 16;
      const unsigned int tg1 = (unsigned int)(t + 1);
      u32x4 d0, d1, d2, d3, e0 = {}, e1 = {}, e2 = {}, e3 = {};
      if (t > 0) {
        const unsigned int* src2 = h2T + (size_t)(t - 1) * 4096 + sr * 512 + sc * 16;
        const unsigned int tg2 = (unsigned int)t;
        for (;;) {
          d0 = load_coh16(src1); d1 = load_coh16(src1 + 4);
          d2 = load_coh16(src1 + 8); d3 = load_coh16(src1 + 12);
          e0 = load_coh16(src2); e1 = load_coh16(src2 + 4);
          e2 = load_coh16(src2 + 8); e3 = load_coh16(src2 + 12);
          VM_WAIT0;
          bool ok = true;
#pragma unroll
          for (int j = 0; j < 4; ++j) {
            ok &= (d0[j] >> 16) == tg1; ok &= (d1[j] >> 16) == tg1;
            ok &= (d2[j] >> 16) == tg1; ok &= (d3[j] >> 16) == tg1;
            ok &= (e0[j] >> 16) == tg2; ok &= (e1[j] >> 16) == tg2;
            ok &= (e2[j] >> 16) == tg2; ok &= (e3[j] >> 16) == tg2;
          }
          if (__ballot(ok) == ~0ULL) break;
          __builtin_amdgcn_s_sleep(1);
        }
      } else {
        for (;;) {
          d0 = load_coh16(src1); d1 = load_coh16(src1 + 4);
          d2 = load_coh16(src1 + 8); d3 = load_coh16(src1 + 12);
          VM_WAIT0;
          bool ok = true;
#pragma unroll
          for (int j = 0; j < 4; ++j) {
            ok &= (d0[j] >> 16) == tg1; ok &= (d1[j] >> 16) == tg1;
            ok &= (d2[j] >> 16) == tg1; ok &= (d3[j] >> 16) == tg1;
          }
          if (__ballot(ok) == ~0ULL) break;
          __builtin_amdgcn_s_sleep(1);
        }
      }
      *(u32x4*)(hlds + sb0) =
          u32x4{(d0[0] & 0xffffu) | (d0[1] << 16), (d0[2] & 0xffffu) | (d0[3] << 16),
                (d1[0] & 0xffffu) | (d1[1] << 16), (d1[2] & 0xffffu) | (d1[3] << 16)};
      *(u32x4*)(hlds + sb1) =
          u32x4{(d2[0] & 0xffffu) | (d2[1] << 16), (d2[2] & 0xffffu) | (d2[3] << 16),
                (d3[0] & 0xffffu) | (d3[1] << 16), (d3[2] & 0xffffu) | (d3[3] << 16)};
      *(u32x4*)(hlds + sb2) =
          u32x4{(e0[0] & 0xffffu) | (e0[1] << 16), (e0[2] & 0xffffu) | (e0[3] << 16),
                (e1[0] & 0xffffu) | (e1[1] << 16), (e1[2] & 0xffffu) | (e1[3] << 16)};
      *(u32x4*)(hlds + sb3) =
          u32x4{(e2[0] & 0xffffu) | (e2[1] << 16), (e2[2] & 0xffffu) | (e2[3] << 16),
                (e3[0] & 0xffffu) | (e3[1] << 16), (e3[2] & 0xffffu) | (e3[3] << 16)};
    }
    __syncthreads();  // staging complete

    // ---- A-frags (conflict-free swizzled ds_read_b128) + MFMA ----
    f32x4 a0 = {}, a1 = {}, a2 = {}, a3 = {};
#pragma unroll
    for (int kt = 0; kt < NKT; kt += 4) {
      s16x8 x0 = *(const s16x8*)(hlds + ((row * RB + (kt + 0) * 64 + grp * 16) ^ (row << 4)));
      s16x8 x1 = *(const s16x8*)(hlds + ((row * RB + (kt + 1) * 64 + grp * 16) ^ (row << 4)));
      s16x8 x2 = *(const s16x8*)(hlds + ((row * RB + (kt + 2) * 64 + grp * 16) ^ (row << 4)));
      s16x8 x3 = *(const s16x8*)(hlds + ((row * RB + (kt + 3) * 64 + grp * 16) ^ (row << 4)));
      a0 = __builtin_amdgcn_mfma_f32_16x16x32_bf16(x0, bfr[kt + 0], a0, 0, 0, 0);
      a1 = __builtin_amdgcn_mfma_f32_16x16x32_bf16(x1, bfr[kt + 1], a1, 0, 0, 0);
      a2 = __builtin_amdgcn_mfma_f32_16x16x32_bf16(x2, bfr[kt + 2], a2, 0, 0, 0);
      a3 = __builtin_amdgcn_mfma_f32_16x16x32_bf16(x3, bfr[kt + 3], a3, 0, 0, 0);
    }
    f32x4 acc = (a0 + a1) + (a2 + a3);

    // ---- gate exchange: GT[gate][unit][batch] (D: col=unit, row=batch=grp*4+q) ----
    if (grp < 2) *(f32x4*)(GT + g * 128 + unit * 8 + grp * 4) = acc;
    __syncthreads();

    // ---- pointwise (wave 0), tagged h store ----
    if (g == 0) {
      const unsigned int tago = (unsigned int)(t + 1) << 16;
#pragma unroll
      for (int r = 0; r < 2; ++r) {
        const int u = r * 8 + pu;
        float gi = GT[0 + u * 8 + pb];
        float gf = GT[128 + u * 8 + pb];
        float gg = GT[256 + u * 8 + pb];
        float go = GT[384 + u * 8 + pb];
        if constexpr (IS_L1) {
          gi += xv[r][0]; gf += xv[r][1]; gg += xv[r][2]; go += xv[r][3];
        } else {
          gi += bias_g[r][0]; gf += bias_g[r][1]; gg += bias_g[r][2]; go += bias_g[r][3];
        }
        float& cc = r ? cst1 : cst0;
        cc = sigf(gf) * cc + sigf(gi) * tanhfast(gg);
        const float hv = sigf(go) * tanhfast(cc);
        const unsigned int hb16 = f2bf(hv);
        unsigned int* hT = IS_L1 ? h1T : h2T;
        ASTORE(hT + (size_t)t * 4096 + pb * 512 + u0 + u, hb16 | tago);
        if constexpr (!IS_L1)
          h2out[(size_t)(t * 8 + pb) * 512 + u0 + u] = (unsigned short)hb16;
      }
    }
  }
}

__global__ __launch_bounds__(256, 1) void lstm_kernel(
    const float* __restrict__ xg1t,
    const unsigned short* __restrict__ whh1,
    const unsigned short* __restrict__ wih2,
    const unsigned short* __restrict__ whh2,
    const float* __restrict__ bias2,
    unsigned int* __restrict__ h1T, unsigned int* __restrict__ h2T,
    unsigned short* __restrict__ h2out) {
  __shared__ __align__(16) char hlds[16384];
  __shared__ float GT[512];
  const int wg = blockIdx.x, tid = threadIdx.x;
  if (wg < 32)
    lstm_side<true>(wg, tid, xg1t, whh1, nullptr, nullptr, h1T, h2T, h2out, hlds, GT);
  else
    lstm_side<false>(wg - 32, tid, xg1t, wih2, whh2, bias2, h1T, h2T, h2out, hlds, GT);
}

// ---------------- host launch ----------------
extern "C" void kernel_launch(void* const* d_in, const int* in_sizes, int n_in,
                              void* d_out, int out_size, void* d_ws, size_t ws_size,
                              hipStream_t stream) {
  (void)in_sizes; (void)n_in; (void)out_size; (void)ws_size;
  const int* inp = (const int*)d_in[0];
  const float* wte = (const float*)d_in[1];
  const float* W_ih = (const float*)d_in[2];
  const float* W_hh = (const float*)d_in[3];
  const float* b_ih = (const float*)d_in[4];
  const float* b_hh = (const float*)d_in[5];
  const float* fc_w = (const float*)d_in[6];
  const float* fc_b = (const float*)d_in[7];
  float* out = (float*)d_out;

  // Large intermediates inside d_out (1 GB; fully overwritten by the final FC GEMM).
  char* ob = (char*)d_out;
  float* xg1t = (float*)(ob);                                    // [  0, 64M) [t*8+b][2048]
  unsigned int* h1T = (unsigned int*)(ob + (64u << 20));         // [ 64, 80M) tagged u32
  unsigned int* h2T = (unsigned int*)(ob + (80u << 20));         // [ 80, 96M) tagged u32
  unsigned short* x_bf = (unsigned short*)(ob + (96u << 20));    // [ 96,104M)
  unsigned short* whh_bf = (unsigned short*)(ob + (104u << 20)); // [104,108M)
  unsigned short* wih_bf = (unsigned short*)(ob + (108u << 20)); // [108,112M)

  char* ws = (char*)d_ws;  // within proven 43 MiB footprint
  unsigned short* fcw_bf = (unsigned short*)(ws);                // [ 0,32M)
  float* bias12 = (float*)(ws + (32u << 20));                    // 16 KiB
  unsigned short* h2bf = (unsigned short*)(ws + (35u << 20));    // [35,43M) [t*8+b][512]

  hipMemsetAsync(ob + (64u << 20), 0, 32u << 20, stream);  // clear h tags (honest sync/replay)
  embed_kernel<<<8192, 256, 0, stream>>>(inp, wte, x_bf);
  cvt_bf16_kernel<<<2048, 256, 0, stream>>>(W_ih, wih_bf, 2 * 2048 * 512 / 4);
  cvt_bf16_kernel<<<2048, 256, 0, stream>>>(W_hh, whh_bf, 2 * 2048 * 512 / 4);
  cvt_bf16_kernel<<<16000, 256, 0, stream>>>(fc_w, fcw_bf, 32000 * 512 / 4);
  bias_sum_kernel<<<16, 256, 0, stream>>>(b_ih, b_hh, bias12, 4096);
  // xg1t[t*8+b][g] = x @ W_ih0^T + (b_ih0 + b_hh0)
  gemm_bt<2><<<64 * 16, 256, 0, stream>>>(x_bf, wih_bf, xg1t, bias12, 8192, 2048, 512);
  lstm_kernel<<<64, 256, 0, stream>>>(xg1t, whh_bf, wih_bf + (size_t)2048 * 512,
                                      whh_bf + (size_t)2048 * 512, bias12 + 2048,
                                      h1T, h2T, h2bf);
  // logits = h2 @ fc_w^T + fc_b  (A rows t*8+b -> C rows b*1024+t)
  gemm_bt<1><<<64 * 250, 256, 0, stream>>>(h2bf, fcw_bf, out, fc_b, 8192, 32000, 512);
}